// Round 1
// baseline (80.227 us; speedup 1.0000x reference)
//
#include <hip/hip_runtime.h>

// InnerProductNetwork: x (B, 32, 16) fp32 -> out (B, 496) fp32
// out[b][pidx(i,j)] = dot(x[b,i,:], x[b,j,:]) for i<j.
// Upper triangle of G = X @ X^T with X = x[b] (32x16); one
// v_mfma_f32_32x32x16_bf16 per batch/wave computes the full Gram matrix.
// A-frag == B-frag for this shape (m=lane&31, k=(lane>>5)*8+e).
//
// This revision vs. previous (79.4 us):
//  - __launch_bounds__(256, 8): force regalloc <=64 VGPR -> 8 waves/EU
//    (32 waves/CU) instead of the 4 waves/EU floor the old (256,4) allowed.
//  - No __syncthreads(): each wave only touches its own so[wave] slice;
//    a same-wave s_waitcnt lgkmcnt(0) orders scatter-writes before readback.
//    Removes inter-wave convoying + the barrier's full vmcnt drain, and
//    allows early-exit structure.
//  - v_cvt_pk_bf16_f32 (RNE, same rounding as the old manual path): 4 VALU
//    instead of ~40 for the fp32->bf16 convert on the critical chain.
// Memory-bound floor: 66 MB HBM traffic -> ~11 us at 6.3 TB/s.

typedef short bf16x8 __attribute__((ext_vector_type(8)));
typedef float f32x16 __attribute__((ext_vector_type(16)));

#define NFIELD 32
#define EMBED  16
#define NPAIR  496    // 32*31/2
#define BATCH_F 512   // NFIELD*EMBED floats per batch

__global__ __launch_bounds__(256, 8)
void ipnn_mfma(const float* __restrict__ x, float* __restrict__ out, int nb) {
  // per-wave 2KiB output staging slice (496 floats used, 512 for alignment)
  __shared__ __align__(16) float so[4][BATCH_F];
  const int wave = threadIdx.x >> 6;
  const int lane = threadIdx.x & 63;
  const int b = blockIdx.x * 4 + wave;   // one batch per wave
  const int m = lane & 31;               // field row this lane loads
  const int h = lane >> 5;               // k-half (0: k=0..7, 1: k=8..15)

  if (b >= nb) return;                   // no barrier below -> early exit OK

  // Load x[b][m][8h .. 8h+8) : 8 contiguous floats = 2x float4, directly in
  // MFMA A/B fragment layout. Wave covers the full 2 KiB batch contiguously.
  const float4* gp = (const float4*)(x + (size_t)b * BATCH_F);
  const int fi = m * 4 + h * 2;
  float4 f0 = gp[fi];
  float4 f1 = gp[fi + 1];

  // fp32 -> bf16 RNE, packed: dst.lo = bf16(src0), dst.hi = bf16(src1).
  unsigned p0, p1, p2, p3;
  asm("v_cvt_pk_bf16_f32 %0, %1, %2" : "=v"(p0) : "v"(f0.x), "v"(f0.y));
  asm("v_cvt_pk_bf16_f32 %0, %1, %2" : "=v"(p1) : "v"(f0.z), "v"(f0.w));
  asm("v_cvt_pk_bf16_f32 %0, %1, %2" : "=v"(p2) : "v"(f1.x), "v"(f1.y));
  asm("v_cvt_pk_bf16_f32 %0, %1, %2" : "=v"(p3) : "v"(f1.z), "v"(f1.w));
  union { unsigned u[4]; bf16x8 v; } au;
  au.u[0] = p0; au.u[1] = p1; au.u[2] = p2; au.u[3] = p3;
  bf16x8 a = au.v;

  f32x16 acc = {};
  // G = X * X^T : A-frag == B-frag (same lane mapping, same k order).
  acc = __builtin_amdgcn_mfma_f32_32x32x16_bf16(a, a, acc, 0, 0, 0);

  // Scatter upper-triangle entries into this wave's LDS slice at their
  // output offsets. C/D layout (m74/m101): col = lane&31,
  // row = (r&3) + 8*(r>>2) + 4*h. (Row/col swap immunity: G symmetric.)
  float* sw = so[wave];
  const int col = m;
#pragma unroll
  for (int r = 0; r < 16; ++r) {
    const int row = (r & 3) + 8 * (r >> 2) + 4 * h;
    if (row < col) {
      // pidx = sum of row lengths before `row` + (col - row - 1)
      const int pidx = ((row * (63 - row)) >> 1) + (col - row - 1);
      sw[pidx] = acc[r];
    }
  }

  // Same-wave LDS RAW: drain this wave's ds_writes before its ds_reads.
  // ("memory" clobber orders the surrounding LDS ops across the asm.)
  asm volatile("s_waitcnt lgkmcnt(0)" ::: "memory");

  if (lane < 62) {
    // Coalesced readback + store: 496 floats = 62 lanes x 2 float4.
    float4 v0 = *(const float4*)(sw + 4 * lane);          // dwords [0,248)
    float4 v1 = *(const float4*)(sw + 4 * lane + 248);    // dwords [248,496)
    float4* op = (float4*)(out + (size_t)b * NPAIR);
    op[lane] = v0;
    op[lane + 62] = v1;
  }
}

extern "C" void kernel_launch(void* const* d_in, const int* in_sizes, int n_in,
                              void* d_out, int out_size, void* d_ws, size_t ws_size,
                              hipStream_t stream) {
  const float* x = (const float*)d_in[0];
  float* out = (float*)d_out;
  const int nb = in_sizes[0] / BATCH_F;   // 16384
  const int grid = (nb + 3) / 4;          // 4 batches (waves) per block
  ipnn_mfma<<<grid, 256, 0, stream>>>(x, out, nb);
}